// Round 5
// baseline (91.417 us; speedup 1.0000x reference)
//
#include <hip/hip_runtime.h>

namespace {
constexpr int BF = 4;        // frames
constexpr int NA = 4000;     // atoms per frame
constexpr int NPAD = 4096;   // padded K
constexpr int N8 = NPAD / 8; // 512 k-groups
constexpr int AD = 29;       // kx: 0..28
constexpr int CD = 57;       // ky/kz: -28..28 (index - 28)
constexpr float TWOPI_F = 6.28318530717958647692f;
constexpr float FPI = 39.47841760435743f;        // (2*pi)^2
constexpr float KSQMAX = 9.869604401089358f;     // (2*pi/2)^2
constexpr float SELF_C = 0.06349363593424097f;   // 1 / (sigma * (2*pi)^1.5)
constexpr size_t YSTR = (size_t)N8 * 64 * 8;     // per-frame table elems = 262144
constexpr size_t SPLANE = (size_t)BF * AD * 4096; // S elems per chunk plane
}

typedef short bfrag __attribute__((ext_vector_type(8)));   // 8 bf16 (4 VGPR)
typedef float f32x4 __attribute__((ext_vector_type(4)));
typedef unsigned short u16x8 __attribute__((ext_vector_type(8)));

__device__ __forceinline__ unsigned short f2bf(float x) {  // RNE f32->bf16
  unsigned u = __float_as_uint(x);
  u += 0x7fffu + ((u >> 16) & 1u);
  return (unsigned short)(u >> 16);
}
__device__ __forceinline__ float2 cmul(float2 a, float2 b) {
  return make_float2(a.x * b.x - a.y * b.y, a.x * b.y + a.y * b.x);
}
// p^m for m in [0,31] via square-and-select
__device__ __forceinline__ float2 cpow_m(float c, float s, int m) {
  float2 r = make_float2(1.f, 0.f);
  float2 x = make_float2(c, s);
  if (m & 1) r = x;
#pragma unroll
  for (int b = 1; b < 5; ++b) {
    x = cmul(x, x);
    const float2 t = cmul(r, x);
    if (m & (1 << b)) r = t;
  }
  return r;
}

// ---------------------------------------------------------------------------
// Fused prep. blockIdx.x < 128: Y/Z tables (wave per n8-group, lane = col).
// blockIdx.x >= 128: T table (thread per atom).
// ---------------------------------------------------------------------------
__global__ __launch_bounds__(256)
void ew_prep(const float* __restrict__ pos, const float* __restrict__ q,
             const float* __restrict__ cm,
             float* __restrict__ Yfr, float* __restrict__ Yfi,
             unsigned short* __restrict__ Zpr, unsigned short* __restrict__ Zpi,
             float2* __restrict__ T)
{
  const int f = blockIdx.y;
  if (blockIdx.x < 128) {
    const int n8 = blockIdx.x * 4 + (threadIdx.x >> 6);   // 0..511
    const int col = threadIdx.x & 63;
    const int e = col - 28;
    const int m = (e < 0) ? -e : e;
    const bool valid = col < CD;
    const float by = cm[f * 9 + 4], bz = cm[f * 9 + 8];

    float yr[8], yi[8], zr[8], zi[8];
#pragma unroll
    for (int i = 0; i < 8; ++i) {
      const int n = n8 * 8 + i;
      const bool ok = n < NA;
      const int gn = f * NA + n;
      const float y = ok ? pos[gn * 3 + 1] : 0.f;
      const float z = ok ? pos[gn * 3 + 2] : 0.f;
      {
        float rev = y / by; rev -= floorf(rev);
        float s, c; __sincosf(TWOPI_F * rev, &s, &c);
        float2 r = cpow_m(c, s, m);
        if (e < 0) r.y = -r.y;
        yr[i] = valid ? r.x : 0.f;
        yi[i] = valid ? r.y : 0.f;
      }
      {
        float rev = z / bz; rev -= floorf(rev);
        float s, c; __sincosf(TWOPI_F * rev, &s, &c);
        float2 r = cpow_m(c, s, m);
        if (e < 0) r.y = -r.y;
        zr[i] = valid ? r.x : 0.f;
        zi[i] = valid ? r.y : 0.f;
      }
    }
    const size_t base = (size_t)f * YSTR + (size_t)n8 * 512 + (size_t)col * 8;
    *(float4*)(Yfr + base)     = make_float4(yr[0], yr[1], yr[2], yr[3]);
    *(float4*)(Yfr + base + 4) = make_float4(yr[4], yr[5], yr[6], yr[7]);
    *(float4*)(Yfi + base)     = make_float4(yi[0], yi[1], yi[2], yi[3]);
    *(float4*)(Yfi + base + 4) = make_float4(yi[4], yi[5], yi[6], yi[7]);
    u16x8 zpr, zpi;
#pragma unroll
    for (int i = 0; i < 8; ++i) { zpr[i] = f2bf(zr[i]); zpi[i] = f2bf(zi[i]); }
    *(u16x8*)(Zpr + base) = zpr;
    *(u16x8*)(Zpi + base) = zpi;
  } else {
    const int n = (blockIdx.x - 128) * 256 + threadIdx.x;   // 0..4095
    const float bx = cm[f * 9 + 0];
    const bool ok = n < NA;
    const int gn = f * NA + n;
    const float x = ok ? pos[gn * 3 + 0] : 0.f;
    const float qq = ok ? q[gn] : 0.f;
    float rev = x / bx; rev -= floorf(rev);
    float s, c; __sincosf(TWOPI_F * rev, &s, &c);
    const float2 p = make_float2(c, s);
    float2 cur = make_float2(qq, 0.f);
    float2* tp = T + (size_t)f * AD * NPAD + n;
#pragma unroll 1
    for (int a = 0; a < AD; ++a) {
      tp[(size_t)a * NPAD] = cur;
      cur = cmul(cur, p);
    }
  }
}

// ---------------------------------------------------------------------------
// MFMA S-accumulation, K-split with Y-prefetch pipeline.
// Block = (a, f, chunk), 4 waves; wave w owns b-strip [16w,16w+16).
// Stores raw partial S[ch][f][a][b][c] (float2), coalesced.
// ---------------------------------------------------------------------------
__global__ __launch_bounds__(256)
void ew_smfma(const float* __restrict__ Yfr, const float* __restrict__ Yfi,
              const unsigned short* __restrict__ Zpr,
              const unsigned short* __restrict__ Zpi,
              const float2* __restrict__ T, float2* __restrict__ Sp,
              int ktn)
{
  const int a = blockIdx.x, f = blockIdx.y, ch = blockIdx.z;
  const int tid = threadIdx.x;
  const int w = tid >> 6, lane = tid & 63;
  const int g = lane >> 4, r16 = lane & 15;
  const int b0 = 16 * w;

  f32x4 Sr[4], Si[4];
#pragma unroll
  for (int ct = 0; ct < 4; ++ct) {
    Sr[ct] = (f32x4){0.f, 0.f, 0.f, 0.f};
    Si[ct] = (f32x4){0.f, 0.f, 0.f, 0.f};
  }

  const size_t ybase = (size_t)f * YSTR + (size_t)(b0 + r16) * 8 + (size_t)g * 512;
  const size_t zbase = (size_t)f * YSTR + (size_t)r16 * 8 + (size_t)g * 512;
  const float2* tp = T + ((size_t)f * AD + a) * NPAD + g * 8;
  const size_t ko0 = (size_t)ch * ktn * 2048;
  const float4* yr4 = (const float4*)(Yfr + ybase + ko0);   // +512 float4 per kt
  const float4* yi4 = (const float4*)(Yfi + ybase + ko0);

  // prologue: load kt tile 0 (Y only; T and Z stay inline)
  float4 cyr0 = yr4[0], cyr1 = yr4[1];
  float4 cyi0 = yi4[0], cyi1 = yi4[1];

  for (int kti = 0; kti < ktn; ++kti) {
    float4 nyr0, nyr1, nyi0, nyi1;
    const bool hasNext = (kti + 1) < ktn;
    if (hasNext) {
      const size_t o = (size_t)(kti + 1) * 512;
      nyr0 = yr4[o]; nyr1 = yr4[o + 1];
      nyi0 = yi4[o]; nyi1 = yi4[o + 1];
    }
    const int kt = ch * ktn + kti;
    const size_t ko = (size_t)kt * 2048;
    const float4* t4 = (const float4*)(tp + (size_t)kt * 32);
    const float4 t01 = t4[0], t23 = t4[1], t45 = t4[2], t67 = t4[3];

    const float tr[8] = {t01.x, t01.z, t23.x, t23.z, t45.x, t45.z, t67.x, t67.z};
    const float ti[8] = {t01.y, t01.w, t23.y, t23.w, t45.y, t45.w, t67.y, t67.w};
    const float yr[8] = {cyr0.x, cyr0.y, cyr0.z, cyr0.w, cyr1.x, cyr1.y, cyr1.z, cyr1.w};
    const float yi[8] = {cyi0.x, cyi0.y, cyi0.z, cyi0.w, cyi1.x, cyi1.y, cyi1.z, cyi1.w};

    float ur[8], ui[8];
#pragma unroll
    for (int i = 0; i < 8; ++i) {
      const float mm = ti[i] * yi[i];
      ur[i] = fmaf(tr[i], yr[i], -mm);
      ui[i] = fmaf(tr[i], yi[i], ti[i] * yr[i]);
    }
    union { unsigned u[4]; bfrag v; } UR, UI, UN;
#pragma unroll
    for (int k = 0; k < 4; ++k) {
      asm("v_cvt_pk_bf16_f32 %0, %1, %2" : "=v"(UR.u[k]) : "v"(ur[2*k]), "v"(ur[2*k+1]));
      asm("v_cvt_pk_bf16_f32 %0, %1, %2" : "=v"(UI.u[k]) : "v"(ui[2*k]), "v"(ui[2*k+1]));
    }
#pragma unroll
    for (int k = 0; k < 4; ++k) UN.u[k] = UI.u[k] ^ 0x80008000u;

#pragma unroll
    for (int ct = 0; ct < 4; ++ct) {
      const bfrag Zr8 = *(const bfrag*)(Zpr + zbase + ko + (size_t)ct * 128);
      const bfrag Zi8 = *(const bfrag*)(Zpi + zbase + ko + (size_t)ct * 128);
      Sr[ct] = __builtin_amdgcn_mfma_f32_16x16x32_bf16(UR.v, Zr8, Sr[ct], 0, 0, 0);
      Sr[ct] = __builtin_amdgcn_mfma_f32_16x16x32_bf16(UN.v, Zi8, Sr[ct], 0, 0, 0);
      Si[ct] = __builtin_amdgcn_mfma_f32_16x16x32_bf16(UR.v, Zi8, Si[ct], 0, 0, 0);
      Si[ct] = __builtin_amdgcn_mfma_f32_16x16x32_bf16(UI.v, Zr8, Si[ct], 0, 0, 0);
    }
    if (hasNext) { cyr0 = nyr0; cyr1 = nyr1; cyi0 = nyi0; cyi1 = nyi1; }
  }

  // store partial S: D-frag row = b0 + 4g + rg, col = ct*16 + r16
  const size_t sbase = (size_t)ch * SPLANE + ((size_t)f * AD + a) * 4096;
#pragma unroll
  for (int ct = 0; ct < 4; ++ct) {
#pragma unroll
    for (int rg = 0; rg < 4; ++rg) {
      const int b = b0 + 4 * g + rg;
      const int c = ct * 16 + r16;
      Sp[sbase + (size_t)b * 64 + c] = make_float2(Sr[ct][rg], Si[ct][rg]);
    }
  }
}

// ---------------------------------------------------------------------------
// Reduce chunk partials + k-space weights (identical formula to R3/R4).
// Block (x=cell/256, y=a, z=f). Self-energy folded into (a==0, x==0) blocks.
// ---------------------------------------------------------------------------
__global__ __launch_bounds__(256)
void ew_reduce(const float2* __restrict__ Sp, const float* __restrict__ cm,
               const float* __restrict__ q, float* __restrict__ out, int nch)
{
  const int a = blockIdx.y, f = blockIdx.z;
  const int cell = blockIdx.x * 256 + threadIdx.x;   // 0..4095
  const int b = cell >> 6, c = cell & 63;
  float Sr = 0.f, Si = 0.f;
  const size_t base = ((size_t)f * AD + a) * 4096 + cell;
  for (int ch = 0; ch < nch; ++ch) {
    const float2 p = Sp[(size_t)ch * SPLANE + base];
    Sr += p.x; Si += p.y;
  }
  const float bx = cm[f * 9 + 0], by = cm[f * 9 + 4], bz = cm[f * 9 + 8];
  const float invV = 1.f / (bx * by * bz);
  const float fac = (a > 0) ? 2.f : 1.f;
  const float aterm = (float)(a * a) / (bx * bx);
  const int bv = b - 28, cv = c - 28;
  const float ksq = FPI * (aterm + (float)(bv * bv) / (by * by)
                          + (float)(cv * cv) / (bz * bz));
  float val = 0.f;
  if (ksq > 0.f && ksq <= KSQMAX) {
    const float wgt = __expf(-0.5f * ksq) / ksq * fac * invV;
    val = wgt * (Sr * Sr + Si * Si);
  }
  for (int off = 32; off > 0; off >>= 1) val += __shfl_down(val, off);
  __shared__ float wsum[4];
  const int w = threadIdx.x >> 6;
  if ((threadIdx.x & 63) == 0) wsum[w] = val;
  __syncthreads();
  if (threadIdx.x == 0)
    atomicAdd(&out[f], wsum[0] + wsum[1] + wsum[2] + wsum[3]);

  if (a == 0 && blockIdx.x == 0) {   // block-uniform: fold in self-energy
    __syncthreads();
    float s = 0.f;
    for (int i = threadIdx.x; i < NA; i += 256) {
      const float qq = q[f * NA + i];
      s += qq * qq;
    }
    for (int off = 32; off > 0; off >>= 1) s += __shfl_down(s, off);
    if ((threadIdx.x & 63) == 0) wsum[w] = s;
    __syncthreads();
    if (threadIdx.x == 0)
      atomicAdd(&out[f], -(wsum[0] + wsum[1] + wsum[2] + wsum[3]) * SELF_C);
  }
}

extern "C" void kernel_launch(void* const* d_in, const int* in_sizes, int n_in,
                              void* d_out, int out_size, void* d_ws, size_t ws_size,
                              hipStream_t stream) {
  const float* pos = (const float*)d_in[0];   // (B*N, 3)
  const float* q   = (const float*)d_in[1];   // (B*N, 1)
  const float* cm  = (const float*)d_in[2];   // (B, 3, 3)
  float* out = (float*)d_out;                 // (B,)

  char* ws = (char*)d_ws;
  const size_t MB = 1024 * 1024;
  float* Yfr = (float*)(ws);                       // 4 MB
  float* Yfi = (float*)(ws + 4 * MB);              // 4 MB
  unsigned short* Zpr = (unsigned short*)(ws + 8 * MB);   // 2 MB
  unsigned short* Zpi = (unsigned short*)(ws + 10 * MB);  // 2 MB
  float2* T  = (float2*)(ws + 12 * MB);            // 3.8 MB
  float2* Sp = (float2*)(ws + 16 * MB);            // nch * 3.8 MB

  const size_t sp_need16 = 16 * SPLANE * sizeof(float2);
  const int nch = (ws_size >= 16 * MB + sp_need16) ? 16 : 8;
  const int ktn = (NPAD / 32) / nch;

  hipMemsetAsync(d_out, 0, out_size * sizeof(float), stream);
  ew_prep<<<dim3(144, BF), 256, 0, stream>>>(pos, q, cm, Yfr, Yfi, Zpr, Zpi, T);
  ew_smfma<<<dim3(AD, BF, nch), 256, 0, stream>>>(Yfr, Yfi, Zpr, Zpi, T, Sp, ktn);
  ew_reduce<<<dim3(4096 / 256, AD, BF), 256, 0, stream>>>(Sp, cm, q, out, nch);
}

// Round 6
// 82.695 us; speedup vs baseline: 1.1055x; 1.1055x over previous
//
#include <hip/hip_runtime.h>

namespace {
constexpr int BF = 4;        // frames
constexpr int NA = 4000;     // atoms per frame
constexpr int NPAD = 4096;   // padded K
constexpr int N8 = NPAD / 8; // 512 k-groups
constexpr int AD = 29;       // kx: 0..28
constexpr int CD = 57;       // ky/kz: -28..28 (index - 28)
constexpr int NCH = 8;       // K-chunks
constexpr int KTN = 16;      // k-tiles (32 atoms) per chunk
constexpr float TWOPI_F = 6.28318530717958647692f;
constexpr float FPI = 39.47841760435743f;        // (2*pi)^2
constexpr float KSQMAX = 9.869604401089358f;     // (2*pi/2)^2
constexpr float SELF_C = 0.06349363593424097f;   // 1 / (sigma * (2*pi)^1.5)
constexpr size_t YSTR = (size_t)N8 * 64 * 8;     // per-frame table elems = 262144
constexpr size_t SPLANE = (size_t)BF * AD * 4096; // S elems per chunk plane
}

typedef short bfrag __attribute__((ext_vector_type(8)));   // 8 bf16 (4 VGPR)
typedef float f32x4 __attribute__((ext_vector_type(4)));
typedef unsigned short u16x8 __attribute__((ext_vector_type(8)));

__device__ __forceinline__ unsigned short f2bf(float x) {  // RNE f32->bf16
  unsigned u = __float_as_uint(x);
  u += 0x7fffu + ((u >> 16) & 1u);
  return (unsigned short)(u >> 16);
}
__device__ __forceinline__ float2 cmul(float2 a, float2 b) {
  return make_float2(a.x * b.x - a.y * b.y, a.x * b.y + a.y * b.x);
}
// p^m for m in [0,31] via square-and-select
__device__ __forceinline__ float2 cpow_m(float c, float s, int m) {
  float2 r = make_float2(1.f, 0.f);
  float2 x = make_float2(c, s);
  if (m & 1) r = x;
#pragma unroll
  for (int b = 1; b < 5; ++b) {
    x = cmul(x, x);
    const float2 t = cmul(r, x);
    if (m & (1 << b)) r = t;
  }
  return r;
}
// LDS tile swizzle (involution on bits [5:4] ^= bits [11:10] of byte offset)
__device__ __forceinline__ int swz(int byte) {
  return byte ^ (((byte >> 10) & 3) << 4);
}

// ---------------------------------------------------------------------------
// Fused prep. blockIdx.x < 128: Y(packed bf16 u32)/Z tables, wave per n8,
// lane = col. blockIdx.x >= 128: T table (thread per atom).
// ---------------------------------------------------------------------------
__global__ __launch_bounds__(256)
void ew_prep(const float* __restrict__ pos, const float* __restrict__ q,
             const float* __restrict__ cm,
             unsigned* __restrict__ Yp,
             unsigned short* __restrict__ Zpr, unsigned short* __restrict__ Zpi,
             float2* __restrict__ T)
{
  const int f = blockIdx.y;
  if (blockIdx.x < 128) {
    const int n8 = blockIdx.x * 4 + (threadIdx.x >> 6);   // 0..511
    const int col = threadIdx.x & 63;
    const int e = col - 28;
    const int m = (e < 0) ? -e : e;
    const bool valid = col < CD;
    const float by = cm[f * 9 + 4], bz = cm[f * 9 + 8];

    unsigned yp[8];
    float zr[8], zi[8];
#pragma unroll
    for (int i = 0; i < 8; ++i) {
      const int n = n8 * 8 + i;
      const bool ok = n < NA;
      const int gn = f * NA + n;
      const float y = ok ? pos[gn * 3 + 1] : 0.f;
      const float z = ok ? pos[gn * 3 + 2] : 0.f;
      {
        float rev = y / by; rev -= floorf(rev);
        float s, c; __sincosf(TWOPI_F * rev, &s, &c);
        float2 r = cpow_m(c, s, m);
        if (e < 0) r.y = -r.y;
        const float yr = valid ? r.x : 0.f;
        const float yi = valid ? r.y : 0.f;
        yp[i] = ((unsigned)f2bf(yi) << 16) | (unsigned)f2bf(yr);
      }
      {
        float rev = z / bz; rev -= floorf(rev);
        float s, c; __sincosf(TWOPI_F * rev, &s, &c);
        float2 r = cpow_m(c, s, m);
        if (e < 0) r.y = -r.y;
        zr[i] = valid ? r.x : 0.f;
        zi[i] = valid ? r.y : 0.f;
      }
    }
    const size_t base = (size_t)f * YSTR + (size_t)n8 * 512 + (size_t)col * 8;
    *(uint4*)(Yp + base)     = make_uint4(yp[0], yp[1], yp[2], yp[3]);
    *(uint4*)(Yp + base + 4) = make_uint4(yp[4], yp[5], yp[6], yp[7]);
    u16x8 zpr, zpi;
#pragma unroll
    for (int i = 0; i < 8; ++i) { zpr[i] = f2bf(zr[i]); zpi[i] = f2bf(zi[i]); }
    *(u16x8*)(Zpr + base) = zpr;
    *(u16x8*)(Zpi + base) = zpi;
  } else {
    const int n = (blockIdx.x - 128) * 256 + threadIdx.x;   // 0..4095
    const float bx = cm[f * 9 + 0];
    const bool ok = n < NA;
    const int gn = f * NA + n;
    const float x = ok ? pos[gn * 3 + 0] : 0.f;
    const float qq = ok ? q[gn] : 0.f;
    float rev = x / bx; rev -= floorf(rev);
    float s, c; __sincosf(TWOPI_F * rev, &s, &c);
    const float2 p = make_float2(c, s);
    float2 cur = make_float2(qq, 0.f);
    float2* tp = T + (size_t)f * AD * NPAD + n;
#pragma unroll 1
    for (int a = 0; a < AD; ++a) {
      tp[(size_t)a * NPAD] = cur;
      cur = cmul(cur, p);
    }
  }
}

// ---------------------------------------------------------------------------
// MFMA S-accumulation. Block = (a-pair, f, chunk), 4 waves, nch=8.
// Z staged in LDS (dbuf, swizzled), shared by 4 waves x 2 a-values.
// Y bf16-packed u32, register double-buffered. T loaded inline (L1-hot).
// ---------------------------------------------------------------------------
__global__ __launch_bounds__(256)
void ew_smfma(const unsigned* __restrict__ Yp,
              const unsigned short* __restrict__ Zpr,
              const unsigned short* __restrict__ Zpi,
              const float2* __restrict__ T, float2* __restrict__ Sp)
{
  const int ag = blockIdx.x, f = blockIdx.y, ch = blockIdx.z;
  const int a0 = 2 * ag, a1 = a0 + 1;
  const bool has1 = a1 < AD;
  const int tid = threadIdx.x;
  const int w = tid >> 6, lane = tid & 63;
  const int g = lane >> 4, r16 = lane & 15;
  const int b0 = 16 * w;

  __shared__ unsigned short zbuf[2][2][2048];   // [dbuf][r/i][elems], 16 KB

  f32x4 S0r[4], S0i[4], S1r[4], S1i[4];
#pragma unroll
  for (int ct = 0; ct < 4; ++ct) {
    S0r[ct] = (f32x4){0.f, 0.f, 0.f, 0.f}; S0i[ct] = (f32x4){0.f, 0.f, 0.f, 0.f};
    S1r[ct] = (f32x4){0.f, 0.f, 0.f, 0.f}; S1i[ct] = (f32x4){0.f, 0.f, 0.f, 0.f};
  }

  // Y: lane reads 8 u32 per kt at [f][.][b0+r16][.]
  const unsigned* ybase = Yp + (size_t)f * YSTR + (size_t)(b0 + r16) * 8
                        + (size_t)g * 512 + (size_t)ch * KTN * 2048;
  // Z global source: thread-linear 16B slices of the 2048-elem kt tile
  const size_t zgbase = (size_t)f * YSTR + (size_t)ch * KTN * 2048 + (size_t)tid * 8;
  // T: per (a), lane group g reads atoms g*8.. (broadcast within 16 lanes)
  const float2* tp0 = T + ((size_t)f * AD + a0) * NPAD + (size_t)ch * KTN * 32 + g * 8;
  const float2* tp1 = T + ((size_t)f * AD + (has1 ? a1 : a0)) * NPAD
                    + (size_t)ch * KTN * 32 + g * 8;

  // LDS addresses
  char* const zb = (char*)&zbuf[0][0][0];
  const int wr_off = swz(tid * 16);                         // write slot
  const int rd_base = g * 1024 + r16 * 16;                  // frag base (pre-ct)

  // ---- prologue: stage kt tile 0 into buf 0 ----
  u16x8 zr_st = *(const u16x8*)(Zpr + zgbase);
  u16x8 zi_st = *(const u16x8*)(Zpi + zgbase);
  *(u16x8*)(zb + wr_off) = zr_st;
  *(u16x8*)(zb + 4096 + wr_off) = zi_st;
  uint4 ycur0 = *(const uint4*)(ybase);
  uint4 ycur1 = *(const uint4*)(ybase + 4);
  __syncthreads();

  for (int kti = 0; kti < KTN; ++kti) {
    const int knx = (kti + 1 < KTN) ? (kti + 1) : kti;      // clamped prefetch
    // issue next-tile loads early (latency hides under compute)
    zr_st = *(const u16x8*)(Zpr + zgbase + (size_t)knx * 2048);
    zi_st = *(const u16x8*)(Zpi + zgbase + (size_t)knx * 2048);
    const uint4 ynx0 = *(const uint4*)(ybase + (size_t)knx * 2048);
    const uint4 ynx1 = *(const uint4*)(ybase + (size_t)knx * 2048 + 4);

    // unpack Y (bf16 pair -> f32)
    float yr[8], yi[8];
    {
      const unsigned yu[8] = {ycur0.x, ycur0.y, ycur0.z, ycur0.w,
                              ycur1.x, ycur1.y, ycur1.z, ycur1.w};
#pragma unroll
      for (int i = 0; i < 8; ++i) {
        yr[i] = __uint_as_float(yu[i] << 16);
        yi[i] = __uint_as_float(yu[i] & 0xffff0000u);
      }
    }
    char* const cb = zb + ((kti & 1) ? 8192 : 0);

    // ---- a0 ----
    {
      const float4* t4 = (const float4*)(tp0 + (size_t)kti * 32);
      const float4 t01 = t4[0], t23 = t4[1], t45 = t4[2], t67 = t4[3];
      const float tr[8] = {t01.x, t01.z, t23.x, t23.z, t45.x, t45.z, t67.x, t67.z};
      const float ti[8] = {t01.y, t01.w, t23.y, t23.w, t45.y, t45.w, t67.y, t67.w};
      float ur[8], ui[8];
#pragma unroll
      for (int i = 0; i < 8; ++i) {
        ur[i] = fmaf(tr[i], yr[i], -(ti[i] * yi[i]));
        ui[i] = fmaf(tr[i], yi[i], ti[i] * yr[i]);
      }
      union { unsigned u[4]; bfrag v; } UR, UI, UN;
#pragma unroll
      for (int k = 0; k < 4; ++k) {
        asm("v_cvt_pk_bf16_f32 %0, %1, %2" : "=v"(UR.u[k]) : "v"(ur[2*k]), "v"(ur[2*k+1]));
        asm("v_cvt_pk_bf16_f32 %0, %1, %2" : "=v"(UI.u[k]) : "v"(ui[2*k]), "v"(ui[2*k+1]));
      }
#pragma unroll
      for (int k = 0; k < 4; ++k) UN.u[k] = UI.u[k] ^ 0x80008000u;
#pragma unroll
      for (int ct = 0; ct < 4; ++ct) {
        const int ro = swz(rd_base + ct * 256);
        const bfrag Zr8 = *(const bfrag*)(cb + ro);
        const bfrag Zi8 = *(const bfrag*)(cb + 4096 + ro);
        S0r[ct] = __builtin_amdgcn_mfma_f32_16x16x32_bf16(UR.v, Zr8, S0r[ct], 0, 0, 0);
        S0r[ct] = __builtin_amdgcn_mfma_f32_16x16x32_bf16(UN.v, Zi8, S0r[ct], 0, 0, 0);
        S0i[ct] = __builtin_amdgcn_mfma_f32_16x16x32_bf16(UR.v, Zi8, S0i[ct], 0, 0, 0);
        S0i[ct] = __builtin_amdgcn_mfma_f32_16x16x32_bf16(UI.v, Zr8, S0i[ct], 0, 0, 0);
      }
    }
    // ---- a1 ----
    if (has1) {
      const float4* t4 = (const float4*)(tp1 + (size_t)kti * 32);
      const float4 t01 = t4[0], t23 = t4[1], t45 = t4[2], t67 = t4[3];
      const float tr[8] = {t01.x, t01.z, t23.x, t23.z, t45.x, t45.z, t67.x, t67.z};
      const float ti[8] = {t01.y, t01.w, t23.y, t23.w, t45.y, t45.w, t67.y, t67.w};
      float ur[8], ui[8];
#pragma unroll
      for (int i = 0; i < 8; ++i) {
        ur[i] = fmaf(tr[i], yr[i], -(ti[i] * yi[i]));
        ui[i] = fmaf(tr[i], yi[i], ti[i] * yr[i]);
      }
      union { unsigned u[4]; bfrag v; } UR, UI, UN;
#pragma unroll
      for (int k = 0; k < 4; ++k) {
        asm("v_cvt_pk_bf16_f32 %0, %1, %2" : "=v"(UR.u[k]) : "v"(ur[2*k]), "v"(ur[2*k+1]));
        asm("v_cvt_pk_bf16_f32 %0, %1, %2" : "=v"(UI.u[k]) : "v"(ui[2*k]), "v"(ui[2*k+1]));
      }
#pragma unroll
      for (int k = 0; k < 4; ++k) UN.u[k] = UI.u[k] ^ 0x80008000u;
#pragma unroll
      for (int ct = 0; ct < 4; ++ct) {
        const int ro = swz(rd_base + ct * 256);
        const bfrag Zr8 = *(const bfrag*)(cb + ro);
        const bfrag Zi8 = *(const bfrag*)(cb + 4096 + ro);
        S1r[ct] = __builtin_amdgcn_mfma_f32_16x16x32_bf16(UR.v, Zr8, S1r[ct], 0, 0, 0);
        S1r[ct] = __builtin_amdgcn_mfma_f32_16x16x32_bf16(UN.v, Zi8, S1r[ct], 0, 0, 0);
        S1i[ct] = __builtin_amdgcn_mfma_f32_16x16x32_bf16(UR.v, Zi8, S1i[ct], 0, 0, 0);
        S1i[ct] = __builtin_amdgcn_mfma_f32_16x16x32_bf16(UI.v, Zr8, S1i[ct], 0, 0, 0);
      }
    }
    // ---- stage next tile into the other buffer, one barrier ----
    char* const nb = zb + ((kti & 1) ? 0 : 8192);
    *(u16x8*)(nb + wr_off) = zr_st;
    *(u16x8*)(nb + 4096 + wr_off) = zi_st;
    ycur0 = ynx0; ycur1 = ynx1;
    __syncthreads();
  }

  // store partial S: D-frag row = b0 + 4g + rg, col = ct*16 + r16
  const size_t sb0 = (size_t)ch * SPLANE + ((size_t)f * AD + a0) * 4096;
#pragma unroll
  for (int ct = 0; ct < 4; ++ct)
#pragma unroll
    for (int rg = 0; rg < 4; ++rg) {
      const int b = b0 + 4 * g + rg;
      const int c = ct * 16 + r16;
      Sp[sb0 + (size_t)b * 64 + c] = make_float2(S0r[ct][rg], S0i[ct][rg]);
    }
  if (has1) {
    const size_t sb1 = (size_t)ch * SPLANE + ((size_t)f * AD + a1) * 4096;
#pragma unroll
    for (int ct = 0; ct < 4; ++ct)
#pragma unroll
      for (int rg = 0; rg < 4; ++rg) {
        const int b = b0 + 4 * g + rg;
        const int c = ct * 16 + r16;
        Sp[sb1 + (size_t)b * 64 + c] = make_float2(S1r[ct][rg], S1i[ct][rg]);
      }
  }
}

// ---------------------------------------------------------------------------
// Reduce chunk partials + k-space weights (identical formula to R3-R5).
// Self-energy folded into (a==0, x==0) blocks.
// ---------------------------------------------------------------------------
__global__ __launch_bounds__(256)
void ew_reduce(const float2* __restrict__ Sp, const float* __restrict__ cm,
               const float* __restrict__ q, float* __restrict__ out, int nch)
{
  const int a = blockIdx.y, f = blockIdx.z;
  const int cell = blockIdx.x * 256 + threadIdx.x;   // 0..4095
  const int b = cell >> 6, c = cell & 63;
  float Sr = 0.f, Si = 0.f;
  const size_t base = ((size_t)f * AD + a) * 4096 + cell;
  for (int ch = 0; ch < nch; ++ch) {
    const float2 p = Sp[(size_t)ch * SPLANE + base];
    Sr += p.x; Si += p.y;
  }
  const float bx = cm[f * 9 + 0], by = cm[f * 9 + 4], bz = cm[f * 9 + 8];
  const float invV = 1.f / (bx * by * bz);
  const float fac = (a > 0) ? 2.f : 1.f;
  const float aterm = (float)(a * a) / (bx * bx);
  const int bv = b - 28, cv = c - 28;
  const float ksq = FPI * (aterm + (float)(bv * bv) / (by * by)
                          + (float)(cv * cv) / (bz * bz));
  float val = 0.f;
  if (ksq > 0.f && ksq <= KSQMAX) {
    const float wgt = __expf(-0.5f * ksq) / ksq * fac * invV;
    val = wgt * (Sr * Sr + Si * Si);
  }
  for (int off = 32; off > 0; off >>= 1) val += __shfl_down(val, off);
  __shared__ float wsum[4];
  const int w = threadIdx.x >> 6;
  if ((threadIdx.x & 63) == 0) wsum[w] = val;
  __syncthreads();
  if (threadIdx.x == 0)
    atomicAdd(&out[f], wsum[0] + wsum[1] + wsum[2] + wsum[3]);

  if (a == 0 && blockIdx.x == 0) {   // block-uniform: fold in self-energy
    __syncthreads();
    float s = 0.f;
    for (int i = threadIdx.x; i < NA; i += 256) {
      const float qq = q[f * NA + i];
      s += qq * qq;
    }
    for (int off = 32; off > 0; off >>= 1) s += __shfl_down(s, off);
    if ((threadIdx.x & 63) == 0) wsum[w] = s;
    __syncthreads();
    if (threadIdx.x == 0)
      atomicAdd(&out[f], -(wsum[0] + wsum[1] + wsum[2] + wsum[3]) * SELF_C);
  }
}

extern "C" void kernel_launch(void* const* d_in, const int* in_sizes, int n_in,
                              void* d_out, int out_size, void* d_ws, size_t ws_size,
                              hipStream_t stream) {
  const float* pos = (const float*)d_in[0];   // (B*N, 3)
  const float* q   = (const float*)d_in[1];   // (B*N, 1)
  const float* cm  = (const float*)d_in[2];   // (B, 3, 3)
  float* out = (float*)d_out;                 // (B,)

  char* ws = (char*)d_ws;
  const size_t MB = 1024 * 1024;
  unsigned* Yp = (unsigned*)(ws);                         // 4 MB (u32-packed bf16)
  unsigned short* Zpr = (unsigned short*)(ws + 4 * MB);   // 2 MB
  unsigned short* Zpi = (unsigned short*)(ws + 6 * MB);   // 2 MB
  float2* T  = (float2*)(ws + 8 * MB);                    // 3.8 MB
  float2* Sp = (float2*)(ws + 12 * MB);                   // 30.4 MB

  hipMemsetAsync(d_out, 0, out_size * sizeof(float), stream);
  ew_prep<<<dim3(144, BF), 256, 0, stream>>>(pos, q, cm, Yp, Zpr, Zpi, T);
  ew_smfma<<<dim3((AD + 1) / 2, BF, NCH), 256, 0, stream>>>(Yp, Zpr, Zpi, T, Sp);
  ew_reduce<<<dim3(4096 / 256, AD, BF), 256, 0, stream>>>(Sp, cm, q, out, NCH);
}